// Round 1
// baseline (320.716 us; speedup 1.0000x reference)
//
#include <hip/hip_runtime.h>
#include <hip/hip_bf16.h>
#include <cstddef>

// Problem dims
#define NN 768
#define CC 384
#define HH 12
#define DPP 128
// ws layout (float offsets). Total = 1622016 + 7077888 floats = 34.8 MB.
#define OFF_Q   0
#define OFF_K   294912
#define OFF_V   589824
#define OFF_QP  884736
#define OFF_KP  995328
#define OFF_VP  1105920
#define OFF_WTD 1216512
#define OFF_PW  1511424
#define OFF_LOG 1622016

// ---------------------------------------------------------------------------
// Kernel 1: fused projection GEMM.  C[i][n] = single[i,:] . W[n,:] + b[n]
// Virtual N = 1584 = 3*384 (q,k,v) + 3*144 (qp,kp,vp).
// BM=64, BN=48, BK=32, 256 threads, each computes 4x3.
// ---------------------------------------------------------------------------
__global__ __launch_bounds__(256) void k_proj(
    const float* __restrict__ single,
    const float* __restrict__ qw, const float* __restrict__ qb,
    const float* __restrict__ kw, const float* __restrict__ kb,
    const float* __restrict__ vw, const float* __restrict__ vb,
    const float* __restrict__ qpw, const float* __restrict__ qpb,
    const float* __restrict__ kpw, const float* __restrict__ kpb,
    const float* __restrict__ vpw, const float* __restrict__ vpb,
    float* __restrict__ ws)
{
    __shared__ float As[64][33];
    __shared__ float Bs[48][33];
    const int tid = threadIdx.x;
    const int i0 = blockIdx.y * 64;
    const int n0 = blockIdx.x * 48;
    const int tx = tid & 15, ty = tid >> 4;
    float acc[4][3] = {};
    for (int k0 = 0; k0 < CC; k0 += 32) {
        #pragma unroll
        for (int l = tid; l < 64 * 32; l += 256) {
            int r = l >> 5, c = l & 31;
            As[r][c] = single[(size_t)(i0 + r) * CC + k0 + c];
        }
        #pragma unroll
        for (int l = tid; l < 48 * 32; l += 256) {
            int r = l >> 5, c = l & 31;
            int n = n0 + r;
            const float* wp; int row;
            if (n < 1152) { int m = n / CC; row = n - m * CC; wp = (m == 0) ? qw : ((m == 1) ? kw : vw); }
            else { int np = n - 1152; int m = np / 144; row = np - m * 144; wp = (m == 0) ? qpw : ((m == 1) ? kpw : vpw); }
            Bs[r][c] = wp[(size_t)row * CC + k0 + c];
        }
        __syncthreads();
        #pragma unroll
        for (int kk = 0; kk < 32; ++kk) {
            float av[4], bv[3];
            #pragma unroll
            for (int a = 0; a < 4; ++a) av[a] = As[ty * 4 + a][kk];
            #pragma unroll
            for (int b = 0; b < 3; ++b) bv[b] = Bs[tx * 3 + b][kk];
            #pragma unroll
            for (int a = 0; a < 4; ++a)
                #pragma unroll
                for (int b = 0; b < 3; ++b)
                    acc[a][b] = fmaf(av[a], bv[b], acc[a][b]);
        }
        __syncthreads();
    }
    #pragma unroll
    for (int a = 0; a < 4; ++a) {
        int i = i0 + ty * 4 + a;
        #pragma unroll
        for (int b = 0; b < 3; ++b) {
            int n = n0 + tx * 3 + b;
            float bias; size_t dst;
            if (n < 1152) {
                int m = n / CC; int c = n - m * CC;
                bias = ((m == 0) ? qb : ((m == 1) ? kb : vb))[c];
                dst = (size_t)m * 294912 + (size_t)i * CC + c;
            } else {
                int np = n - 1152; int m = np / 144; int c = np - m * 144;
                bias = ((m == 0) ? qpb : ((m == 1) ? kpb : vpb))[c];
                dst = (size_t)OFF_QP + (size_t)m * 110592 + (size_t)i * 144 + c;
            }
            ws[dst] = acc[a][b] + bias;
        }
    }
}

// ---------------------------------------------------------------------------
// Kernel 2: rotate+translate the local points in place (qp/kp/vp -> qg/kg/vg)
// g[j] = sum_i p[i]*R[i][j] + T[j]
// ---------------------------------------------------------------------------
__global__ __launch_bounds__(256) void k_to_global(
    const float* __restrict__ rot, const float* __restrict__ trans, float* __restrict__ ws)
{
    int id = blockIdx.x * 256 + threadIdx.x;   // 3 * 768 * 48 = 110592 total
    if (id >= 3 * NN * 48) return;
    int t3 = id / (NN * 48);
    int rem = id - t3 * (NN * 48);
    int n = rem / 48;
    int hp = rem - n * 48;
    float* arr = ws + OFF_QP + (size_t)t3 * 110592 + (size_t)n * 144 + hp * 3;
    float p0 = arr[0], p1 = arr[1], p2 = arr[2];
    const float* R = rot + (size_t)n * 9;
    const float* T = trans + (size_t)n * 3;
    arr[0] = p0 * R[0] + p1 * R[3] + p2 * R[6] + T[0];
    arr[1] = p0 * R[1] + p1 * R[4] + p2 * R[7] + T[1];
    arr[2] = p0 * R[2] + p1 * R[5] + p2 * R[8] + T[2];
}

// ---------------------------------------------------------------------------
// Kernel 3: full attention logits (pair bias + scalar qk + point distance).
// Block: 4 query rows (i0..i0+3) x 256 keys (one j per thread).
// logits[h][i][j] = pb_b[h] + pair[i,j,:].pb_w[h,:]
//                 + scale * (q[i,h,:].k[j,h,:]) - 0.5*scale*sum_pd (qg-kg)^2
// ---------------------------------------------------------------------------
__global__ __launch_bounds__(256) void k_logits(
    const float* __restrict__ pair,
    const float* __restrict__ pbw, const float* __restrict__ pbb,
    const float* __restrict__ q, const float* __restrict__ k,
    const float* __restrict__ qg, const float* __restrict__ kg,
    float* __restrict__ logits)
{
    const float scale = 0.17677669529663687f;   // 32^-0.5
    __shared__ float pbw_s[HH * DPP];
    const int tid = threadIdx.x;
    for (int idx = tid; idx < HH * DPP; idx += 256) pbw_s[idx] = pbw[idx];
    __syncthreads();
    const int i0 = blockIdx.x * 4;
    const int j = blockIdx.y * 256 + tid;

    float acc[4][12];
    #pragma unroll
    for (int ii = 0; ii < 4; ++ii)
        #pragma unroll
        for (int h = 0; h < HH; ++h) acc[ii][h] = pbb[h];

    // pair bias: each thread streams its own 512B pair row (float4; per-lane
    // consecutive 16B within a 128B line -> full line utilization), weights
    // broadcast from LDS.
    #pragma unroll
    for (int ii = 0; ii < 4; ++ii) {
        const float4* pr = (const float4*)(pair + ((size_t)(i0 + ii) * NN + j) * DPP);
        #pragma unroll 4
        for (int k4 = 0; k4 < 32; ++k4) {
            float4 pv = pr[k4];
            #pragma unroll
            for (int h = 0; h < HH; ++h) {
                float4 w = ((const float4*)pbw_s)[h * 32 + k4];
                acc[ii][h] = fmaf(pv.x, w.x, acc[ii][h]);
                acc[ii][h] = fmaf(pv.y, w.y, acc[ii][h]);
                acc[ii][h] = fmaf(pv.z, w.z, acc[ii][h]);
                acc[ii][h] = fmaf(pv.w, w.w, acc[ii][h]);
            }
        }
    }

    // scalar qk + point distance; q/qg rows are wave-uniform (s_loads).
    #pragma unroll
    for (int h = 0; h < HH; ++h) {
        float kf[32];
        const float4* kp4 = (const float4*)(k + (size_t)j * CC + h * 32);
        #pragma unroll
        for (int t = 0; t < 8; ++t) {
            float4 tv = kp4[t];
            kf[4 * t + 0] = tv.x; kf[4 * t + 1] = tv.y; kf[4 * t + 2] = tv.z; kf[4 * t + 3] = tv.w;
        }
        float kgf[12];
        const float4* kg4 = (const float4*)(kg + (size_t)j * 144 + h * 12);
        #pragma unroll
        for (int t = 0; t < 3; ++t) {
            float4 tv = kg4[t];
            kgf[4 * t + 0] = tv.x; kgf[4 * t + 1] = tv.y; kgf[4 * t + 2] = tv.z; kgf[4 * t + 3] = tv.w;
        }
        #pragma unroll
        for (int ii = 0; ii < 4; ++ii) {
            const float* qrow = q + (size_t)(i0 + ii) * CC + h * 32;
            float dt = 0.f;
            #pragma unroll
            for (int c = 0; c < 32; ++c) dt = fmaf(kf[c], qrow[c], dt);
            const float* qgrow = qg + (size_t)(i0 + ii) * 144 + h * 12;
            float pt = 0.f;
            #pragma unroll
            for (int e = 0; e < 12; ++e) { float d2 = qgrow[e] - kgf[e]; pt = fmaf(d2, d2, pt); }
            float lv = acc[ii][h] + scale * dt - 0.5f * scale * pt;
            logits[((size_t)h * NN + (i0 + ii)) * NN + j] = lv;  // coalesced in j
        }
    }
}

// ---------------------------------------------------------------------------
// Kernel 4: softmax over j + weighted sums (scalar v and point vg together).
// Block: (i-tile of 8) x one head. 256 threads.
// Outputs per block: 8 rows x (32 scalar dims + 12 point dims) = 352.
// ---------------------------------------------------------------------------
__global__ __launch_bounds__(256) void k_soft(
    const float* __restrict__ logits, const float* __restrict__ v, const float* __restrict__ vg,
    float* __restrict__ weighted, float* __restrict__ pw)
{
    __shared__ float att[8][772];
    __shared__ float vt[128][45];
    const int tid = threadIdx.x;
    const int h = blockIdx.y;
    const int i0 = blockIdx.x * 8;

    for (int idx = tid; idx < 8 * 192; idx += 256) {
        int r = idx / 192, c4 = idx - r * 192;
        float4 tv = ((const float4*)(logits + ((size_t)h * NN + i0 + r) * NN))[c4];
        float* dp = &att[r][c4 * 4];
        dp[0] = tv.x; dp[1] = tv.y; dp[2] = tv.z; dp[3] = tv.w;
    }
    __syncthreads();
    {   // softmax: 32 lanes per row
        int r = tid >> 5, lane = tid & 31;
        float m = -1e30f;
        for (int jj = lane; jj < NN; jj += 32) m = fmaxf(m, att[r][jj]);
        #pragma unroll
        for (int off = 16; off; off >>= 1) m = fmaxf(m, __shfl_xor(m, off, 32));
        float s = 0.f;
        for (int jj = lane; jj < NN; jj += 32) { float e = __expf(att[r][jj] - m); att[r][jj] = e; s += e; }
        #pragma unroll
        for (int off = 16; off; off >>= 1) s += __shfl_xor(s, off, 32);
        float inv = 1.f / s;
        for (int jj = lane; jj < NN; jj += 32) att[r][jj] *= inv;
    }
    __syncthreads();

    float acc0 = 0.f, acc1 = 0.f;
    const int o0 = tid, o1 = tid + 256;
    const int r0 = o0 / 44, d0 = o0 - r0 * 44;
    const int o1c = (o1 < 352) ? o1 : 351;
    const int r1 = o1c / 44, d1 = o1c - r1 * 44;
    for (int jc = 0; jc < 6; ++jc) {
        for (int idx = tid; idx < 128 * 44; idx += 256) {
            int jj = idx / 44, d = idx - jj * 44;
            int jg = jc * 128 + jj;
            vt[jj][d] = (d < 32) ? v[(size_t)jg * CC + h * 32 + d]
                                 : vg[(size_t)jg * 144 + h * 12 + (d - 32)];
        }
        __syncthreads();
        const float* a0p = &att[r0][jc * 128];
        const float* a1p = &att[r1][jc * 128];
        #pragma unroll 4
        for (int jj = 0; jj < 128; ++jj) {
            acc0 = fmaf(a0p[jj], vt[jj][d0], acc0);
            acc1 = fmaf(a1p[jj], vt[jj][d1], acc1);
        }
        __syncthreads();
    }
    {
        int i = i0 + r0;
        if (d0 < 32) weighted[(size_t)i * CC + h * 32 + d0] = acc0;
        else         pw[(size_t)i * 144 + h * 12 + (d0 - 32)] = acc0;
    }
    if (o1 < 352) {
        int i = i0 + r1;
        if (d1 < 32) weighted[(size_t)i * CC + h * 32 + d1] = acc1;
        else         pw[(size_t)i * 144 + h * 12 + (d1 - 32)] = acc1;
    }
}

// ---------------------------------------------------------------------------
// Kernel 5: point_proj -> (+weighted) -> out proj -> residual -> LayerNorm.
// Block: 4 rows, 384 threads (thread = output channel).
// ---------------------------------------------------------------------------
__global__ __launch_bounds__(384) void k_out(
    const float* __restrict__ single,
    const float* __restrict__ weighted, const float* __restrict__ pwv,
    const float* __restrict__ ptw, const float* __restrict__ ptb,
    const float* __restrict__ outw, const float* __restrict__ outb,
    const float* __restrict__ lng, const float* __restrict__ lnb,
    float* __restrict__ out)
{
    __shared__ float pw_s[4][144];
    __shared__ float tmp_s[4][388];
    __shared__ float red[16];
    const int tid = threadIdx.x;
    const int i0 = blockIdx.x * 4;
    for (int idx = tid; idx < 4 * 144; idx += 384) {
        int r = idx / 144, e = idx - r * 144;
        pw_s[r][e] = pwv[(size_t)(i0 + r) * 144 + e];
    }
    __syncthreads();
    const int c = tid;
    float t[4];
    {
        float a[4] = {0.f, 0.f, 0.f, 0.f};
        const float4* wp4 = (const float4*)(ptw + (size_t)c * 144);
        #pragma unroll 4
        for (int e4 = 0; e4 < 36; ++e4) {
            float4 w4 = wp4[e4];
            #pragma unroll
            for (int r = 0; r < 4; ++r) {
                float4 pv = *(const float4*)&pw_s[r][e4 * 4];
                a[r] = fmaf(w4.x, pv.x, a[r]);
                a[r] = fmaf(w4.y, pv.y, a[r]);
                a[r] = fmaf(w4.z, pv.z, a[r]);
                a[r] = fmaf(w4.w, pv.w, a[r]);
            }
        }
        float pb = ptb[c];
        #pragma unroll
        for (int r = 0; r < 4; ++r)
            t[r] = weighted[(size_t)(i0 + r) * CC + c] + pb + a[r];
    }
    #pragma unroll
    for (int r = 0; r < 4; ++r) tmp_s[r][c] = t[r];
    __syncthreads();
    float o[4];
    {
        float ob = outb[c];
        #pragma unroll
        for (int r = 0; r < 4; ++r) o[r] = ob;
        const float4* wp4 = (const float4*)(outw + (size_t)c * CC);
        #pragma unroll 2
        for (int e4 = 0; e4 < 96; ++e4) {
            float4 w4 = wp4[e4];
            #pragma unroll
            for (int r = 0; r < 4; ++r) {
                float4 tv = *(const float4*)&tmp_s[r][e4 * 4];
                o[r] = fmaf(w4.x, tv.x, o[r]);
                o[r] = fmaf(w4.y, tv.y, o[r]);
                o[r] = fmaf(w4.z, tv.z, o[r]);
                o[r] = fmaf(w4.w, tv.w, o[r]);
            }
        }
        #pragma unroll
        for (int r = 0; r < 4; ++r) o[r] += single[(size_t)(i0 + r) * CC + c];
    }
    float g = lng[c], bb = lnb[c];
    #pragma unroll
    for (int rr = 0; rr < 4; ++rr) {
        float xs = o[rr], xq = o[rr] * o[rr];
        #pragma unroll
        for (int off = 32; off; off >>= 1) {
            xs += __shfl_xor(xs, off, 64);
            xq += __shfl_xor(xq, off, 64);
        }
        __syncthreads();
        if ((tid & 63) == 0) { int w = tid >> 6; red[w] = xs; red[8 + w] = xq; }
        __syncthreads();
        float S = red[0] + red[1] + red[2] + red[3] + red[4] + red[5];
        float Q = red[8] + red[9] + red[10] + red[11] + red[12] + red[13];
        float mu = S * (1.f / 384.f);
        float var = Q * (1.f / 384.f) - mu * mu;
        float rs = rsqrtf(var + 1e-5f);
        out[(size_t)(i0 + rr) * CC + c] = (o[rr] - mu) * rs * g + bb;
    }
}

// ---------------------------------------------------------------------------
extern "C" void kernel_launch(void* const* d_in, const int* in_sizes, int n_in,
                              void* d_out, int out_size, void* d_ws, size_t ws_size,
                              hipStream_t stream)
{
    const float* single = (const float*)d_in[0];
    const float* pair   = (const float*)d_in[1];
    const float* rot    = (const float*)d_in[2];
    const float* trans  = (const float*)d_in[3];
    const float* qw  = (const float*)d_in[4];  const float* qb  = (const float*)d_in[5];
    const float* kw  = (const float*)d_in[6];  const float* kb  = (const float*)d_in[7];
    const float* vw  = (const float*)d_in[8];  const float* vb  = (const float*)d_in[9];
    const float* pbw = (const float*)d_in[10]; const float* pbb = (const float*)d_in[11];
    const float* qpw = (const float*)d_in[12]; const float* qpb = (const float*)d_in[13];
    const float* kpw = (const float*)d_in[14]; const float* kpb = (const float*)d_in[15];
    const float* vpw = (const float*)d_in[16]; const float* vpb = (const float*)d_in[17];
    const float* ptw = (const float*)d_in[18]; const float* ptb = (const float*)d_in[19];
    const float* outw = (const float*)d_in[20]; const float* outb = (const float*)d_in[21];
    const float* lng  = (const float*)d_in[22]; const float* lnb  = (const float*)d_in[23];

    float* ws = (float*)d_ws;   // needs ~34.8 MB
    float* q   = ws + OFF_Q;
    float* k   = ws + OFF_K;
    float* v   = ws + OFF_V;
    float* qg  = ws + OFF_QP;
    float* kg  = ws + OFF_KP;
    float* vg  = ws + OFF_VP;
    float* wtd = ws + OFF_WTD;
    float* pwv = ws + OFF_PW;
    float* logits = ws + OFF_LOG;

    dim3 g1(33, 12);
    hipLaunchKernelGGL(k_proj, g1, dim3(256), 0, stream,
                       single, qw, qb, kw, kb, vw, vb, qpw, qpb, kpw, kpb, vpw, vpb, ws);
    hipLaunchKernelGGL(k_to_global, dim3(432), dim3(256), 0, stream, rot, trans, ws);
    dim3 g3(192, 3);
    hipLaunchKernelGGL(k_logits, g3, dim3(256), 0, stream,
                       pair, pbw, pbb, q, k, qg, kg, logits);
    dim3 g4(96, 12);
    hipLaunchKernelGGL(k_soft, g4, dim3(256), 0, stream, logits, v, vg, wtd, pwv);
    hipLaunchKernelGGL(k_out, dim3(192), dim3(384), 0, stream,
                       single, wtd, pwv, ptw, ptb, outw, outb, lng, lnb, (float*)d_out);
}